// Round 1
// baseline (246.155 us; speedup 1.0000x reference)
//
#include <hip/hip_runtime.h>

#define NCLU 32
#define NDIM 16
#define W_VAR 3.0f
#define W_DIST 1.0f
#define W_REG 0.001f
#define W_SMOOTH 5.0f
#define W_SEED 5.0f

// ws layout:
// bytes [0,8)  double bce_sum   (acc[0])
// bytes [8,16) double seed_sum  (acc[1])
// floats (index into (float*)ws):
enum {
    F_CNT  = 4,            // [4,36)    counts
    F_SV   = 36,           // [36,68)   sum v
    F_SV2  = 68,           // [68,100)  sum v^2
    F_SF   = 100,          // [100,612) sum features [c*16+d]
    F_CM   = 612,          // [612,1124) cluster means
    F_M2   = 1124,         // [1124,1156) |mean|^2
    F_NIV  = 1156,         // [1156,1188) -1/(2 var)
    F_SMALL= 1188,         // small losses (dist+reg+smooth, weighted)
    F_END  = 1192
};

__global__ __launch_bounds__(256)
void k_seg(const float* __restrict__ feat, const float* __restrict__ sd,
           const int* __restrict__ lab, float* __restrict__ ws, int n)
{
    __shared__ float s_cnt[NCLU], s_v[NCLU], s_v2[NCLU], s_f[NCLU * NDIM];
    int tid = threadIdx.x;
    for (int i = tid; i < NCLU; i += 256) { s_cnt[i] = 0.f; s_v[i] = 0.f; s_v2[i] = 0.f; }
    for (int i = tid; i < NCLU * NDIM; i += 256) s_f[i] = 0.f;
    __syncthreads();

    int stride = gridDim.x * 256;
    for (int i = blockIdx.x * 256 + tid; i < n; i += stride) {
        int c = lab[i];
        float2 s2 = ((const float2*)sd)[i];
        float v = expf(s2.y);
        atomicAdd(&s_cnt[c], 1.0f);
        atomicAdd(&s_v[c], v);
        atomicAdd(&s_v2[c], v * v);
        const float4* fp = (const float4*)(feat + (size_t)i * NDIM);
        float4 a = fp[0], b = fp[1], c4 = fp[2], d4 = fp[3];
        float* base = &s_f[c * NDIM];
        atomicAdd(base + 0,  a.x);  atomicAdd(base + 1,  a.y);
        atomicAdd(base + 2,  a.z);  atomicAdd(base + 3,  a.w);
        atomicAdd(base + 4,  b.x);  atomicAdd(base + 5,  b.y);
        atomicAdd(base + 6,  b.z);  atomicAdd(base + 7,  b.w);
        atomicAdd(base + 8,  c4.x); atomicAdd(base + 9,  c4.y);
        atomicAdd(base + 10, c4.z); atomicAdd(base + 11, c4.w);
        atomicAdd(base + 12, d4.x); atomicAdd(base + 13, d4.y);
        atomicAdd(base + 14, d4.z); atomicAdd(base + 15, d4.w);
    }
    __syncthreads();
    for (int i = tid; i < NCLU; i += 256) {
        unsafeAtomicAdd(&ws[F_CNT + i], s_cnt[i]);
        unsafeAtomicAdd(&ws[F_SV  + i], s_v[i]);
        unsafeAtomicAdd(&ws[F_SV2 + i], s_v2[i]);
    }
    for (int i = tid; i < NCLU * NDIM; i += 256)
        unsafeAtomicAdd(&ws[F_SF + i], s_f[i]);
}

__global__ __launch_bounds__(1024)
void k_stats(float* __restrict__ ws)
{
    __shared__ float s_cm[NCLU * NDIM];
    __shared__ float red[1024];
    int tid = threadIdx.x;
    float contrib = 0.f;
    if (tid < NCLU) {
        int c = tid;
        float cnt = ws[F_CNT + c];
        float inv = 1.0f / cnt;
        float var = ws[F_SV + c] * inv;
        float sm  = ws[F_SV2 + c] * inv - var * var;   // E[v^2] - var^2 == mean((v-var)^2)
        float m2 = 0.f;
        for (int d = 0; d < NDIM; ++d) {
            float cm = ws[F_SF + c * NDIM + d] * inv;
            ws[F_CM + c * NDIM + d] = cm;
            s_cm[c * NDIM + d] = cm;
            m2 = fmaf(cm, cm, m2);
        }
        ws[F_M2 + c]  = m2;
        ws[F_NIV + c] = -0.5f / var;
        contrib = W_REG * sqrtf(m2) * (1.0f / NCLU) + W_SMOOTH * sm * (1.0f / NCLU);
    }
    __syncthreads();
    int i = tid >> 5, j = tid & 31;
    if (i != j) {
        float d2 = 0.f;
        for (int d = 0; d < NDIM; ++d) {
            float df = s_cm[i * NDIM + d] - s_cm[j * NDIM + d];
            d2 = fmaf(df, df, d2);
        }
        float dd = sqrtf(d2);
        float h = fmaxf(3.0f - dd, 0.f);   // 2*DELTA_DIST = 3.0
        contrib += W_DIST * h * h * (1.0f / ((NCLU - 1) * NCLU));
    }
    red[tid] = contrib;
    __syncthreads();
    for (int s = 512; s > 0; s >>= 1) {
        if (tid < s) red[tid] += red[tid + s];
        __syncthreads();
    }
    if (tid == 0) ws[F_SMALL] = red[0];
}

__global__ __launch_bounds__(256)
void k_main(const float* __restrict__ feat, const float* __restrict__ sd,
            const int* __restrict__ lab, const float* __restrict__ ws,
            double* __restrict__ acc, int n)
{
    __shared__ float s_cm[NCLU * NDIM];
    __shared__ float s_m2[NCLU], s_niv[NCLU];
    int tid = threadIdx.x;
    for (int i = tid; i < NCLU * NDIM; i += 256) s_cm[i] = ws[F_CM + i];
    if (tid < NCLU) { s_m2[tid] = ws[F_M2 + tid]; s_niv[tid] = ws[F_NIV + tid]; }
    __syncthreads();

    float bce = 0.f, sl = 0.f;
    int stride = gridDim.x * 256;
    for (int i = blockIdx.x * 256 + tid; i < n; i += stride) {
        float f[NDIM];
        const float4* fp = (const float4*)(feat + (size_t)i * NDIM);
        float4 q;
        q = fp[0]; f[0] = q.x;  f[1] = q.y;  f[2] = q.z;  f[3] = q.w;
        q = fp[1]; f[4] = q.x;  f[5] = q.y;  f[6] = q.z;  f[7] = q.w;
        q = fp[2]; f[8] = q.x;  f[9] = q.y;  f[10] = q.z; f[11] = q.w;
        q = fp[3]; f[12] = q.x; f[13] = q.y; f[14] = q.z; f[15] = q.w;
        float f2 = 0.f;
        #pragma unroll
        for (int d = 0; d < NDIM; ++d) f2 = fmaf(f[d], f[d], f2);
        int c0 = lab[i];
        float s0 = sd[2 * (size_t)i];
        float own = 0.f;
        #pragma unroll 4
        for (int c = 0; c < NCLU; ++c) {
            float dot = 0.f;
            #pragma unroll
            for (int d = 0; d < NDIM; ++d) dot = fmaf(f[d], s_cm[c * NDIM + d], dot);
            float D2 = fmaxf(f2 + s_m2[c] - 2.0f * dot, 0.f);
            float lp = D2 * s_niv[c];
            float P = expf(lp);
            float t;
            if (c == c0) { t = fmaxf(lp, -100.f); own = P; }
            else         { t = fmaxf(log1pf(-P), -100.f); }
            bce -= t;
        }
        float e = own - s0;
        sl = fmaf(e, e, sl);
    }

    __shared__ float rb[256], rs[256];
    rb[tid] = bce; rs[tid] = sl;
    __syncthreads();
    for (int s = 128; s > 0; s >>= 1) {
        if (tid < s) { rb[tid] += rb[tid + s]; rs[tid] += rs[tid + s]; }
        __syncthreads();
    }
    if (tid == 0) {
        unsafeAtomicAdd(&acc[0], (double)rb[0]);
        unsafeAtomicAdd(&acc[1], (double)rs[0]);
    }
}

__global__ void k_final(const float* __restrict__ ws, const double* __restrict__ acc,
                        float* __restrict__ out, int n)
{
    float var_loss  = (float)(acc[0] / ((double)n * NCLU));
    float seed_loss = (float)(acc[1] / (double)n);
    out[0] = W_VAR * var_loss + ws[F_SMALL] + W_SEED * seed_loss;
}

extern "C" void kernel_launch(void* const* d_in, const int* in_sizes, int n_in,
                              void* d_out, int out_size, void* d_ws, size_t ws_size,
                              hipStream_t stream)
{
    const float* feat = (const float*)d_in[0];
    const float* sd   = (const float*)d_in[1];
    const int*   lab  = (const int*)d_in[2];
    float*  ws  = (float*)d_ws;
    double* acc = (double*)d_ws;
    int n = in_sizes[2];   // number of points (label count)

    hipMemsetAsync(d_ws, 0, F_END * sizeof(float), stream);
    k_seg  <<<1024, 256, 0, stream>>>(feat, sd, lab, ws, n);
    k_stats<<<1, 1024, 0, stream>>>(ws);
    k_main <<<1024, 256, 0, stream>>>(feat, sd, lab, ws, acc, n);
    k_final<<<1, 1, 0, stream>>>(ws, acc, (float*)d_out, n);
}